// Round 1
// baseline (1747.604 us; speedup 1.0000x reference)
//
#include <hip/hip_runtime.h>

// GCN 2-layer forward on MI355X.
// Inputs: x[N,128] f32, edge_index[2,E] i32, W1[128,32], b1[32], W2[32,2], b2[2], drop_u[N,32]
// Output: [N,2] f32.

#define TPB 256

__global__ void k_init_deg(float* __restrict__ deg, int n) {
    int i = blockIdx.x * TPB + threadIdx.x;
    if (i < n) deg[i] = 1.0f;   // +1 self loop
}

__global__ void k_count_deg(const int* __restrict__ dst, float* __restrict__ deg, int e) {
    int i = blockIdx.x * TPB + threadIdx.x;
    if (i < e) atomicAdd(&deg[dst[i]], 1.0f);  // exact integer counts in fp32 -> deterministic
}

__global__ void k_make_dis(float* __restrict__ deg, int n) {
    int i = blockIdx.x * TPB + threadIdx.x;
    if (i < n) deg[i] = rsqrtf(deg[i]);  // deg buffer becomes dis
}

// h1 = x @ W1 ; agg1 = h1*dis^2 + b1  (self-loop term + bias pre-folded)
// block = 256 threads = 8 rows x 32 channels. W1 (128x32 = 16KB) staged in LDS.
__global__ __launch_bounds__(TPB) void k_gemm1(const float* __restrict__ x,
                                               const float* __restrict__ W1,
                                               const float* __restrict__ b1,
                                               const float* __restrict__ dis,
                                               float* __restrict__ h1,
                                               float* __restrict__ agg1,
                                               int n) {
    __shared__ float w[128 * 32];
    for (int i = threadIdx.x; i < 128 * 32; i += TPB) w[i] = W1[i];
    __syncthreads();

    int lane = threadIdx.x & 31;
    int row  = blockIdx.x * 8 + (threadIdx.x >> 5);
    if (row >= n) return;

    const float4* xr = (const float4*)(x + (size_t)row * 128);
    float acc = 0.0f;
#pragma unroll
    for (int k4 = 0; k4 < 32; ++k4) {
        float4 xv = xr[k4];                       // broadcast within 32-lane group
        acc = fmaf(xv.x, w[(k4 * 4 + 0) * 32 + lane], acc);
        acc = fmaf(xv.y, w[(k4 * 4 + 1) * 32 + lane], acc);
        acc = fmaf(xv.z, w[(k4 * 4 + 2) * 32 + lane], acc);
        acc = fmaf(xv.w, w[(k4 * 4 + 3) * 32 + lane], acc);
    }
    float ds = dis[row];
    h1[(size_t)row * 32 + lane]   = acc;
    agg1[(size_t)row * 32 + lane] = acc * ds * ds + b1[lane];
}

// one thread per (edge, channel): agg1[dst][c] += h1[src][c] * dis[src]*dis[dst]
__global__ __launch_bounds__(TPB) void k_edge_agg1(const int* __restrict__ src,
                                                   const int* __restrict__ dst,
                                                   const float* __restrict__ dis,
                                                   const float* __restrict__ h1,
                                                   float* __restrict__ agg1,
                                                   int e) {
    int t = blockIdx.x * TPB + threadIdx.x;
    int ed = t >> 5, c = t & 31;
    if (ed >= e) return;
    int s = src[ed], d = dst[ed];
    float nrm = dis[s] * dis[d];
    atomicAdd(&agg1[(size_t)d * 32 + c], h1[(size_t)s * 32 + c] * nrm);
}

// h = dropout(relu(agg1)); hw = h @ W2; out_init = hw*dis^2 + b2
// 32 lanes per row, shfl-xor reduction over channels.
__global__ __launch_bounds__(TPB) void k_mid(const float* __restrict__ agg1,
                                             const float* __restrict__ drop_u,
                                             const float* __restrict__ W2,
                                             const float* __restrict__ b2,
                                             const float* __restrict__ dis,
                                             float* __restrict__ hw,
                                             float* __restrict__ out,
                                             int n) {
    int t = blockIdx.x * TPB + threadIdx.x;
    int row = t >> 5, c = t & 31;
    if (row >= n) return;
    float v = agg1[(size_t)row * 32 + c];
    v = fmaxf(v, 0.0f);
    v = (drop_u[(size_t)row * 32 + c] > 0.5f) ? v * 2.0f : 0.0f;
    float p0 = v * W2[c * 2 + 0];
    float p1 = v * W2[c * 2 + 1];
#pragma unroll
    for (int off = 16; off >= 1; off >>= 1) {
        p0 += __shfl_xor(p0, off, 32);
        p1 += __shfl_xor(p1, off, 32);
    }
    if (c == 0) {
        float ds = dis[row], d2 = ds * ds;
        hw[(size_t)row * 2 + 0]  = p0;
        hw[(size_t)row * 2 + 1]  = p1;
        out[(size_t)row * 2 + 0] = p0 * d2 + b2[0];
        out[(size_t)row * 2 + 1] = p1 * d2 + b2[1];
    }
}

// out[dst][j] += hw[src][j] * dis[src]*dis[dst]
__global__ __launch_bounds__(TPB) void k_edge_agg2(const int* __restrict__ src,
                                                   const int* __restrict__ dst,
                                                   const float* __restrict__ dis,
                                                   const float* __restrict__ hw,
                                                   float* __restrict__ out,
                                                   int e) {
    int ed = blockIdx.x * TPB + threadIdx.x;
    if (ed >= e) return;
    int s = src[ed], d = dst[ed];
    float nrm = dis[s] * dis[d];
    const float2 hv = *(const float2*)(hw + (size_t)s * 2);
    atomicAdd(&out[(size_t)d * 2 + 0], hv.x * nrm);
    atomicAdd(&out[(size_t)d * 2 + 1], hv.y * nrm);
}

extern "C" void kernel_launch(void* const* d_in, const int* in_sizes, int n_in,
                              void* d_out, int out_size, void* d_ws, size_t ws_size,
                              hipStream_t stream) {
    const float* x    = (const float*)d_in[0];
    const int*   ei   = (const int*)d_in[1];
    const float* W1   = (const float*)d_in[2];
    const float* b1   = (const float*)d_in[3];
    const float* W2   = (const float*)d_in[4];
    const float* b2   = (const float*)d_in[5];
    const float* dropu= (const float*)d_in[6];
    float* out = (float*)d_out;

    const int N = in_sizes[0] / 128;
    const int E = in_sizes[1] / 2;
    const int* src = ei;
    const int* dst = ei + E;

    // workspace layout (floats): dis[N] | h1[N*32] | agg1[N*32] | hw[N*2]
    float* dis  = (float*)d_ws;
    float* h1   = dis + N;
    float* agg1 = h1 + (size_t)N * 32;
    float* hw   = agg1 + (size_t)N * 32;

    int gN   = (N + TPB - 1) / TPB;
    int gE   = (E + TPB - 1) / TPB;
    int gRow = (N * 32 + TPB - 1) / TPB;          // 32 threads per row
    int gEc  = (int)(((long long)E * 32 + TPB - 1) / TPB);

    k_init_deg<<<gN, TPB, 0, stream>>>(dis, N);
    k_count_deg<<<gE, TPB, 0, stream>>>(dst, dis, E);
    k_make_dis<<<gN, TPB, 0, stream>>>(dis, N);
    k_gemm1<<<(N + 7) / 8, TPB, 0, stream>>>(x, W1, b1, dis, h1, agg1, N);
    k_edge_agg1<<<gEc, TPB, 0, stream>>>(src, dst, dis, h1, agg1, E);
    k_mid<<<gRow, TPB, 0, stream>>>(agg1, dropu, W2, b2, dis, hw, out, N);
    k_edge_agg2<<<gE, TPB, 0, stream>>>(src, dst, dis, hw, out, E);
}

// Round 2
// 1232.443 us; speedup vs baseline: 1.4180x; 1.4180x over previous
//
#include <hip/hip_runtime.h>

// GCN 2-layer forward, CSR pull-mode (no fp32 atomics).
// Inputs: x[N,128] f32, edge_index[2,E] i32, W1[128,32], b1[32], W2[32,2], b2[2], drop_u[N,32]
// Output: [N,2] f32.

#define TPB 256

// ---------- degree / CSR build ----------

__global__ void k_zero_row(int* __restrict__ row, int m) {
    int i = blockIdx.x * TPB + threadIdx.x;
    if (i < m) row[i] = 0;
}

__global__ void k_hist(const int* __restrict__ dst, int* __restrict__ row, int e) {
    int i = blockIdx.x * TPB + threadIdx.x;
    if (i < e) atomicAdd(&row[dst[i]], 1);
}

__global__ void k_dis(const int* __restrict__ row, float* __restrict__ dis, int n) {
    int i = blockIdx.x * TPB + threadIdx.x;
    if (i < n) dis[i] = rsqrtf((float)row[i] + 1.0f);  // +1 self loop
}

// per-block exclusive scan; block totals to aux
__global__ void k_scan_block(int* __restrict__ data, int* __restrict__ aux, int m) {
    __shared__ int buf[2][TPB];
    int t = threadIdx.x;
    int g = blockIdx.x * TPB + t;
    int v = (g < m) ? data[g] : 0;
    buf[0][t] = v;
    __syncthreads();
    int cur = 0;
#pragma unroll
    for (int off = 1; off < TPB; off <<= 1) {
        int nv = buf[cur][t] + (t >= off ? buf[cur][t - off] : 0);
        buf[cur ^ 1][t] = nv;
        __syncthreads();
        cur ^= 1;
    }
    int incl = buf[cur][t];
    if (g < m) data[g] = incl - v;            // exclusive
    if (t == TPB - 1) aux[blockIdx.x] = incl; // block total
}

// single-block exclusive scan of aux (nb <= 1024)
__global__ void k_scan_aux(int* __restrict__ aux, int nb) {
    __shared__ int buf[2][1024];
    int t = threadIdx.x;
    int v = (t < nb) ? aux[t] : 0;
    buf[0][t] = v;
    __syncthreads();
    int cur = 0;
#pragma unroll
    for (int off = 1; off < 1024; off <<= 1) {
        int nv = buf[cur][t] + (t >= off ? buf[cur][t - off] : 0);
        buf[cur ^ 1][t] = nv;
        __syncthreads();
        cur ^= 1;
    }
    if (t < nb) aux[t] = buf[cur][t] - v;     // exclusive
}

__global__ void k_scan_add(int* __restrict__ data, const int* __restrict__ aux, int m) {
    int g = blockIdx.x * TPB + threadIdx.x;
    if (g < m) data[g] += aux[blockIdx.x];
}

// pos = row[d]++ ; csr[pos] = s.  After this, row[d] == start(d+1); start(0)=0.
__global__ void k_scatter(const int* __restrict__ src, const int* __restrict__ dst,
                          int* __restrict__ row, int* __restrict__ csr, int e) {
    int i = blockIdx.x * TPB + threadIdx.x;
    if (i < e) {
        int pos = atomicAdd(&row[dst[i]], 1);
        csr[pos] = src[i];
    }
}

// ---------- dense compute ----------

// h1 = x @ W1 (no bias here). 8 rows x 32 channels per block; W1 in LDS.
__global__ __launch_bounds__(TPB) void k_gemm1(const float* __restrict__ x,
                                               const float* __restrict__ W1,
                                               float* __restrict__ h1, int n) {
    __shared__ float w[128 * 32];
    for (int i = threadIdx.x; i < 128 * 32; i += TPB) w[i] = W1[i];
    __syncthreads();

    int lane = threadIdx.x & 31;
    int row  = blockIdx.x * 8 + (threadIdx.x >> 5);
    if (row >= n) return;

    const float4* xr = (const float4*)(x + (size_t)row * 128);
    float acc = 0.0f;
#pragma unroll
    for (int k4 = 0; k4 < 32; ++k4) {
        float4 xv = xr[k4];
        acc = fmaf(xv.x, w[(k4 * 4 + 0) * 32 + lane], acc);
        acc = fmaf(xv.y, w[(k4 * 4 + 1) * 32 + lane], acc);
        acc = fmaf(xv.z, w[(k4 * 4 + 2) * 32 + lane], acc);
        acc = fmaf(xv.w, w[(k4 * 4 + 3) * 32 + lane], acc);
    }
    h1[(size_t)row * 32 + lane] = acc;
}

// Fused: agg1 = dis[d]*sum_{s in N(d)} h1[s]*dis[s] + h1[d]*dis[d]^2 + b1
//        v = dropout(relu(agg1)); hw[d] = v @ W2
// 32 lanes per dst node (lane = channel).
__global__ __launch_bounds__(TPB) void k_gather1(const int* __restrict__ row,
                                                 const int* __restrict__ csr,
                                                 const float* __restrict__ dis,
                                                 const float* __restrict__ h1,
                                                 const float* __restrict__ b1,
                                                 const float* __restrict__ drop_u,
                                                 const float* __restrict__ W2,
                                                 float* __restrict__ hw, int n) {
    int t = blockIdx.x * TPB + threadIdx.x;
    int d = t >> 5, lane = t & 31;
    if (d >= n) return;

    int start = (d > 0) ? row[d - 1] : 0;
    int end   = row[d];

    float acc = 0.0f;
    int e = start;
    for (; e + 1 < end; e += 2) {
        int s0 = csr[e], s1 = csr[e + 1];
        float w0 = dis[s0], w1 = dis[s1];
        acc = fmaf(h1[(size_t)s0 * 32 + lane], w0, acc);
        acc = fmaf(h1[(size_t)s1 * 32 + lane], w1, acc);
    }
    if (e < end) {
        int s0 = csr[e];
        acc = fmaf(h1[(size_t)s0 * 32 + lane], dis[s0], acc);
    }

    float dd = dis[d];
    float v = acc * dd + h1[(size_t)d * 32 + lane] * dd * dd + b1[lane];
    v = fmaxf(v, 0.0f);
    v = (drop_u[(size_t)d * 32 + lane] > 0.5f) ? v * 2.0f : 0.0f;

    float p0 = v * W2[lane * 2 + 0];
    float p1 = v * W2[lane * 2 + 1];
#pragma unroll
    for (int off = 16; off >= 1; off >>= 1) {
        p0 += __shfl_xor(p0, off, 32);
        p1 += __shfl_xor(p1, off, 32);
    }
    if (lane == 0) {
        hw[(size_t)d * 2 + 0] = p0;
        hw[(size_t)d * 2 + 1] = p1;
    }
}

// out[d] = dis[d]*sum_{s in N(d)} hw[s]*dis[s] + hw[d]*dis[d]^2 + b2
// 32 lanes per dst node (lane = edge slot).
__global__ __launch_bounds__(TPB) void k_gather2(const int* __restrict__ row,
                                                 const int* __restrict__ csr,
                                                 const float* __restrict__ dis,
                                                 const float* __restrict__ hw,
                                                 const float* __restrict__ b2,
                                                 float* __restrict__ out, int n) {
    int t = blockIdx.x * TPB + threadIdx.x;
    int d = t >> 5, lane = t & 31;
    if (d >= n) return;

    int start = (d > 0) ? row[d - 1] : 0;
    int end   = row[d];

    float a0 = 0.0f, a1 = 0.0f;
    for (int e = start + lane; e < end; e += 32) {
        int s = csr[e];
        float w = dis[s];
        float2 hv = ((const float2*)hw)[s];
        a0 = fmaf(hv.x, w, a0);
        a1 = fmaf(hv.y, w, a1);
    }
#pragma unroll
    for (int off = 16; off >= 1; off >>= 1) {
        a0 += __shfl_xor(a0, off, 32);
        a1 += __shfl_xor(a1, off, 32);
    }
    if (lane == 0) {
        float dd = dis[d], d2 = dd * dd;
        float2 hv = ((const float2*)hw)[d];
        out[(size_t)d * 2 + 0] = a0 * dd + hv.x * d2 + b2[0];
        out[(size_t)d * 2 + 1] = a1 * dd + hv.y * d2 + b2[1];
    }
}

extern "C" void kernel_launch(void* const* d_in, const int* in_sizes, int n_in,
                              void* d_out, int out_size, void* d_ws, size_t ws_size,
                              hipStream_t stream) {
    const float* x     = (const float*)d_in[0];
    const int*   ei    = (const int*)d_in[1];
    const float* W1    = (const float*)d_in[2];
    const float* b1    = (const float*)d_in[3];
    const float* W2    = (const float*)d_in[4];
    const float* b2    = (const float*)d_in[5];
    const float* dropu = (const float*)d_in[6];
    float* out = (float*)d_out;

    const int N = in_sizes[0] / 128;
    const int E = in_sizes[1] / 2;
    const int* src = ei;
    const int* dst = ei + E;

    // workspace: dis f32[N] | h1 f32[N*32] | hw f32[N*2] | row i32[N+1] | csr i32[E] | aux i32[1024]
    float* dis = (float*)d_ws;
    float* h1  = dis + N;
    float* hw  = h1 + (size_t)N * 32;
    int*   row = (int*)(hw + (size_t)N * 2);
    int*   csr = row + (N + 1);
    int*   aux = csr + E;

    const int M  = N + 1;                    // scanned elements (row[N] -> E total)
    const int gN = (N + TPB - 1) / TPB;
    const int gM = (M + TPB - 1) / TPB;      // also = #scan blocks, must be <= 1024
    const int gE = (E + TPB - 1) / TPB;
    const int gG = (N * 32 + TPB - 1) / TPB; // 32 lanes per node

    k_zero_row <<<gM, TPB, 0, stream>>>(row, M);
    k_hist     <<<gE, TPB, 0, stream>>>(dst, row, E);
    k_dis      <<<gN, TPB, 0, stream>>>(row, dis, N);
    k_scan_block<<<gM, TPB, 0, stream>>>(row, aux, M);
    k_scan_aux <<<1, 1024, 0, stream>>>(aux, gM);
    k_scan_add <<<gM, TPB, 0, stream>>>(row, aux, M);
    k_scatter  <<<gE, TPB, 0, stream>>>(src, dst, row, csr, E);
    k_gemm1    <<<(N + 7) / 8, TPB, 0, stream>>>(x, W1, h1, N);
    k_gather1  <<<gG, TPB, 0, stream>>>(row, csr, dis, h1, b1, dropu, W2, hw, N);
    k_gather2  <<<gG, TPB, 0, stream>>>(row, csr, dis, hw, b2, out, N);
}